// Round 3
// baseline (26.703 us; speedup 1.0000x reference)
//
#include <hip/hip_runtime.h>
#include <hip/hip_bf16.h>
#include <math.h>

#define Bn   16
#define T1n  256
#define T2n  256
#define Dn   256
#define MPn  32

typedef __attribute__((ext_vector_type(8))) short short8;
typedef __attribute__((ext_vector_type(4))) float f32x4;

typedef const __attribute__((address_space(1))) void* gp_t;
typedef __attribute__((address_space(3))) void* lp_t;

__device__ __forceinline__ void gl_lds16(const void* g, void* l) {
  // async global->LDS, 16B/lane; LDS dest = wave-uniform base + lane*16
  __builtin_amdgcn_global_load_lds((gp_t)g, (lp_t)l, 16, 0, 0);
}

__device__ inline short f2b(float f) {
  __hip_bfloat16 h = __float2bfloat16(f);
  return __builtin_bit_cast(short, h);
}
__device__ inline float b2f(short s) {
  unsigned int u = ((unsigned int)(unsigned short)s) << 16;
  return __builtin_bit_cast(float, u);
}

// swizzled 16B-chunk index within a [64 row][256 d] bf16 tile.
// XOR of row&7 spreads stride-512B column reads across 8 16B slots.
// Involution: write-side source pre-swizzle uses the same XOR.
__device__ inline int swz_chunk(int row, int d8) {
  return row * 32 + (d8 ^ (row & 7));
}

// ---------------- pre-pass: f32 -> bf16 for lt and rt ----------------
__global__ __launch_bounds__(256, 8)
void cvt_bf16_kernel(const float* __restrict__ lt, const float* __restrict__ rt,
                     short* __restrict__ olt, short* __restrict__ ort) {
  int blk = blockIdx.x;
  const float* src;
  short* dst;
  int t;
  if (blk < 512) { src = lt; dst = olt; t = blk * 256 + threadIdx.x; }
  else           { src = rt; dst = ort; t = (blk - 512) * 256 + threadIdx.x; }
  const f32x4* s = reinterpret_cast<const f32x4*>(src + (size_t)t * 8);
  f32x4 f0 = s[0], f1 = s[1];
  short8 v;
  v[0] = f2b(f0.x); v[1] = f2b(f0.y); v[2] = f2b(f0.z); v[3] = f2b(f0.w);
  v[4] = f2b(f1.x); v[5] = f2b(f1.y); v[6] = f2b(f1.z); v[7] = f2b(f1.w);
  *reinterpret_cast<short8*>(dst + (size_t)t * 8) = v;
}

// ---------------- main: per-block 8 m x 64 j, all 256 i ----------------
__global__ __launch_bounds__(512, 2)
void mp_match_kernel(const short* __restrict__ ltb,
                     const short* __restrict__ rtb,
                     const float* __restrict__ kern,
                     float* __restrict__ out) {
  __shared__ short lds_rt[64 * 256];        // 32 KB
  __shared__ short lds_lt[2][64 * 256];     // 64 KB double-buffered

  // 256 blocks. bid%8 = XCD; each XCD gets b in {xcd, xcd+8} (L2 locality).
  const int bid  = blockIdx.x;
  const int xcd  = bid & 7;
  const int q    = bid >> 3;                // 0..31
  const int widx = q & 15;
  const int b    = ((q >> 4) << 3) | xcd;
  const int jblk = widx & 3;
  const int mg   = widx >> 2;               // 4 m-groups of 8
  const int j0   = jblk * 64;

  const int tid  = threadIdx.x;             // 0..511
  const int lane = tid & 63;
  const int w    = tid >> 6;                // wave 0..7 -> its own m
  const int m    = mg * 8 + w;
  const int bl   = lane & 15;
  const int hl   = lane >> 4;

  // staging: 4 chunks (16B) per thread per [64][256] bf16 tile.
  // cidx = it*512 + tid ; linear LDS dest chunk = cidx ; global source
  // pre-swizzled: c = slot ^ (row&7) (involution of the read-side XOR).
  int soff[4];                              // source offset in shorts
  #pragma unroll
  for (int it = 0; it < 4; ++it) {
    int cidx = it * 512 + tid;
    int row = cidx >> 5, slot = cidx & 31;
    int c = slot ^ (row & 7);
    soff[it] = row * 256 + c * 8;
  }
  const int cb0 = (tid & ~63) * 8;          // wave-uniform LDS short-offset base

  // ---- stage rt tile ----
  const short* rbase = rtb + ((size_t)b * T2n + j0) * Dn;
  #pragma unroll
  for (int it = 0; it < 4; ++it)
    gl_lds16(rbase + soff[it], &lds_rt[it * 512 * 8 + cb0]);
  asm volatile("s_waitcnt vmcnt(0)" ::: "memory");
  __syncthreads();

  // ---- issue lt chunk 0 (overlaps bsc computation) ----
  const short* lbase = ltb + (size_t)b * T1n * Dn;
  #pragma unroll
  for (int it = 0; it < 4; ++it)
    gl_lds16(lbase + soff[it], &lds_lt[0][it * 512 * 8 + cb0]);

  // ---- B fragments scaled by k[m], once per block, kept in regs ----
  short8 bsc[4][8];
  {
    const float* kbase = kern + (size_t)m * Dn;
    #pragma unroll
    for (int kk = 0; kk < 8; ++kk) {
      int d8 = kk * 4 + hl;
      const f32x4* kp = reinterpret_cast<const f32x4*>(kbase + d8 * 8);
      f32x4 k0 = kp[0], k1 = kp[1];
      #pragma unroll
      for (int sub = 0; sub < 4; ++sub) {
        int brow = sub * 16 + bl;
        short8 r = *reinterpret_cast<const short8*>(&lds_rt[swz_chunk(brow, d8) * 8]);
        short8 v;
        v[0] = f2b(b2f(r[0]) * k0.x); v[1] = f2b(b2f(r[1]) * k0.y);
        v[2] = f2b(b2f(r[2]) * k0.z); v[3] = f2b(b2f(r[3]) * k0.w);
        v[4] = f2b(b2f(r[4]) * k1.x); v[5] = f2b(b2f(r[5]) * k1.y);
        v[6] = f2b(b2f(r[6]) * k1.z); v[7] = f2b(b2f(r[7]) * k1.w);
        bsc[sub][kk] = v;
      }
    }
  }

  float jmax0 = -1e30f, jmax1 = -1e30f, jmax2 = -1e30f, jmax3 = -1e30f;

  asm volatile("s_waitcnt vmcnt(0)" ::: "memory");
  __syncthreads();                          // lt chunk 0 ready

  for (int ic = 0; ic < 4; ++ic) {
    const int cur = ic & 1;
    if (ic < 3) {                           // prefetch next chunk
      #pragma unroll
      for (int it = 0; it < 4; ++it)
        gl_lds16(lbase + (ic + 1) * 64 * 256 + soff[it],
                 &lds_lt[cur ^ 1][it * 512 * 8 + cb0]);
    }
    const short* lcur = lds_lt[cur];
    #pragma unroll
    for (int it2 = 0; it2 < 4; ++it2) {
      f32x4 acc0 = {0.f,0.f,0.f,0.f}, acc1 = {0.f,0.f,0.f,0.f};
      f32x4 acc2 = {0.f,0.f,0.f,0.f}, acc3 = {0.f,0.f,0.f,0.f};
      int arow = it2 * 16 + bl;
      #pragma unroll
      for (int kk = 0; kk < 8; ++kk) {
        int d8 = kk * 4 + hl;
        short8 a = *reinterpret_cast<const short8*>(&lcur[swz_chunk(arow, d8) * 8]);
        acc0 = __builtin_amdgcn_mfma_f32_16x16x32_bf16(a, bsc[0][kk], acc0, 0, 0, 0);
        acc1 = __builtin_amdgcn_mfma_f32_16x16x32_bf16(a, bsc[1][kk], acc1, 0, 0, 0);
        acc2 = __builtin_amdgcn_mfma_f32_16x16x32_bf16(a, bsc[2][kk], acc2, 0, 0, 0);
        acc3 = __builtin_amdgcn_mfma_f32_16x16x32_bf16(a, bsc[3][kk], acc3, 0, 0, 0);
      }
      jmax0 = fmaxf(jmax0, fmaxf(fmaxf(acc0.x, acc0.y), fmaxf(acc0.z, acc0.w)));
      jmax1 = fmaxf(jmax1, fmaxf(fmaxf(acc1.x, acc1.y), fmaxf(acc1.z, acc1.w)));
      jmax2 = fmaxf(jmax2, fmaxf(fmaxf(acc2.x, acc2.y), fmaxf(acc2.z, acc2.w)));
      jmax3 = fmaxf(jmax3, fmaxf(fmaxf(acc3.x, acc3.y), fmaxf(acc3.z, acc3.w)));
    }
    if (ic < 3) {
      asm volatile("s_waitcnt vmcnt(0)" ::: "memory");
      __syncthreads();
    }
  }

  // ---- cross-lane col-max, redistribute so each lane does ONE tanh ----
  jmax0 = fmaxf(jmax0, __shfl_xor(jmax0, 16));
  jmax0 = fmaxf(jmax0, __shfl_xor(jmax0, 32));
  jmax1 = fmaxf(jmax1, __shfl_xor(jmax1, 16));
  jmax1 = fmaxf(jmax1, __shfl_xor(jmax1, 32));
  jmax2 = fmaxf(jmax2, __shfl_xor(jmax2, 16));
  jmax2 = fmaxf(jmax2, __shfl_xor(jmax2, 32));
  jmax3 = fmaxf(jmax3, __shfl_xor(jmax3, 16));
  jmax3 = fmaxf(jmax3, __shfl_xor(jmax3, 32));
  // after reduce every lane holds all 4 sub values for col = lane&15
  float v = (hl == 0) ? jmax0 : (hl == 1) ? jmax1 : (hl == 2) ? jmax2 : jmax3;
  int j = j0 + hl * 16 + bl;
  out[((size_t)b * T2n + j) * MPn + m] = tanhf(v);
}

extern "C" void kernel_launch(void* const* d_in, const int* in_sizes, int n_in,
                              void* d_out, int out_size, void* d_ws, size_t ws_size,
                              hipStream_t stream) {
  const float* lt   = (const float*)d_in[0];
  const float* rt   = (const float*)d_in[1];
  const float* kern = (const float*)d_in[2];
  float* out = (float*)d_out;

  short* ltb = (short*)d_ws;                       // 1,048,576 shorts (2 MB)
  short* rtb = ltb + (size_t)Bn * T1n * Dn;        // 2 MB more (ws >> 4 MB)

  cvt_bf16_kernel<<<1024, 256, 0, stream>>>(lt, rt, ltb, rtb);
  mp_match_kernel<<<256, 512, 0, stream>>>(ltb, rtb, kern, out);
}